// Round 4
// baseline (699.443 us; speedup 1.0000x reference)
//
#include <hip/hip_runtime.h>
#include <hip/hip_bf16.h>

#define BATCH 4096
#define NGENE 3000
#define HID   6
#define GPT   30
#define T0N   500
#define T1N   50
#define KP    3008    // K padded
#define MROWS 4608    // 3000 (V0 rows) + 1530 (dg mid/root) + 78 pad
#define OUTW  3857
#define BNEPS 1e-5f

typedef __attribute__((ext_vector_type(8))) __bf16 bf16x8;
typedef __attribute__((ext_vector_type(4))) float f32x4;
typedef __attribute__((ext_vector_type(8))) unsigned short ushort8;

__device__ __forceinline__ unsigned short f2bf(float f) {
  unsigned int u = __builtin_bit_cast(unsigned int, f);
  u = (u + 0x7fffu + ((u >> 16) & 1u)) >> 16;
  return (unsigned short)u;
}

__device__ __forceinline__ void gload_lds16(const void* g, void* l) {
  __builtin_amdgcn_global_load_lds(
      (const __attribute__((address_space(1))) unsigned int*)g,
      (__attribute__((address_space(3))) unsigned int*)l, 16, 0, 0);
}

// inline BN scale/shift from raw (sum, sumsq)
__device__ __forceinline__ void bn_ss(const float* __restrict__ st,
                                      const float* __restrict__ gam,
                                      const float* __restrict__ bet,
                                      int c, float& sc, float& sh) {
  float m = st[2 * c] * (1.f / BATCH);
  float v = st[2 * c + 1] * (1.f / BATCH) - m * m;
  sc = gam[c] * rsqrtf(v + BNEPS);
  sh = bet[c] - m * sc;
}

// ================= dispatch 1: all prep, fused by block range =================
// ranges: [0,6016) cast_cell | [6016,12016) v0_build | [12016,14264) cast_wdg_mid
//         [14264,14379) zero_tail | [14379,14397) build_bias | [14397,14423) zero st
__global__ __launch_bounds__(256) void prep(
    const float* __restrict__ cell, const float* __restrict__ Wdg,
    const float* __restrict__ W0, const float* __restrict__ b0,
    const float* __restrict__ bdg,
    ushort8* __restrict__ cellb, unsigned short* __restrict__ abuf,
    float* __restrict__ bias, float* __restrict__ st) {
  int blk = blockIdx.x, tid = threadIdx.x;
  if (blk < 6016) {                       // ---- cast cell -> bf16 [4096][KP]
    int idx = blk * 256 + tid;
    int r = idx / 376, c8 = idx - r * 376;
    int c = c8 * 8;
    ushort8 o = (ushort8)0;
    if (c < NGENE) {
      const float4* p = (const float4*)(cell + (size_t)r * NGENE + c);
      float4 a = p[0], b = p[1];
      o[0] = f2bf(a.x); o[1] = f2bf(a.y); o[2] = f2bf(a.z); o[3] = f2bf(a.w);
      o[4] = f2bf(b.x); o[5] = f2bf(b.y); o[6] = f2bf(b.z); o[7] = f2bf(b.w);
    }
    cellb[idx] = o;
  } else if (blk < 12016) {               // ---- V0[t*6+h][n] = W0[t,h,:]·Wdg[t,:,n]
    int bx = blk - 6016;
    int xb = bx % 12, t = bx / 12;
    int n = xb * 256 + tid;
    if (n >= KP) return;
    bool valid = n < NGENE;
    float x[GPT];
#pragma unroll
    for (int g = 0; g < GPT; ++g)
      x[g] = valid ? Wdg[((size_t)(t * GPT + g)) * NGENE + n] : 0.f;
#pragma unroll
    for (int h = 0; h < HID; ++h) {
      const float* w = W0 + (t * HID + h) * GPT;
      float s = 0.f;
#pragma unroll
      for (int g = 0; g < GPT; ++g) s += x[g] * w[g];
      abuf[((size_t)(t * HID + h)) * KP + n] = valid ? f2bf(s) : (unsigned short)0;
    }
  } else if (blk < 14264) {               // ---- cast Wdg rows 15000..16529 -> abuf 3000+
    int idx = (blk - 12016) * 256 + tid;
    if (idx >= 1530 * 376) return;
    int r = idx / 376, c8 = idx - r * 376;
    int c = c8 * 8;
    ushort8 o = (ushort8)0;
    if (c < NGENE) {
      const float4* p = (const float4*)(Wdg + (size_t)(15000 + r) * NGENE + c);
      float4 a = p[0], b = p[1];
      o[0] = f2bf(a.x); o[1] = f2bf(a.y); o[2] = f2bf(a.z); o[3] = f2bf(a.w);
      o[4] = f2bf(b.x); o[5] = f2bf(b.y); o[6] = f2bf(b.z); o[7] = f2bf(b.w);
    }
    ((ushort8*)abuf)[(size_t)(3000 + r) * 376 + c8] = o;
  } else if (blk < 14379) {               // ---- zero abuf rows 4530..4607
    int idx = (blk - 14264) * 256 + tid;
    if (idx < 78 * 376) ((ushort8*)abuf)[(size_t)4530 * 376 + idx] = (ushort8)0;
  } else if (blk < 14397) {               // ---- bias rows
    int idx = (blk - 14379) * 256 + tid;
    if (idx >= MROWS) return;
    float v = 0.f;
    if (idx < 3000) {
      int t = idx / HID;
      float s = b0[idx];
#pragma unroll
      for (int g = 0; g < GPT; ++g) s += W0[idx * GPT + g] * bdg[t * GPT + g];
      v = s;
    } else if (idx < 4530) {
      v = bdg[15000 + idx - 3000];
    }
    bias[idx] = v;
  } else {                                // ---- zero stats (st0|st1|st2 = 6612 floats)
    int idx = (blk - 14397) * 256 + tid;
    if (idx < 6612) st[idx] = 0.f;
  }
}

// ============ dispatch 2: GEMM + fused layer0 tanh + fused BN stats ============
__global__ __launch_bounds__(256) void gemm_fused(
    const unsigned short* __restrict__ A,    // [MROWS][KP] bf16
    const unsigned short* __restrict__ Bt,   // [BATCH][KP] bf16
    const float* __restrict__ bias,
    float* __restrict__ C,                   // [MROWS][BATCH] fp32
    float* __restrict__ st0) {               // [3000][2] sum/sumsq atomics
  __shared__ unsigned short smem[8192];
  const int tid  = threadIdx.x;
  const int wave = tid >> 6, lane = tid & 63;
  const int wm = wave >> 1, wn = wave & 1;
  const int quad = lane >> 4, fr = lane & 15;
  const int m0 = blockIdx.y * 128, n0 = blockIdx.x * 128;
  const int lrow = lane >> 2;
  const int lcol = (lane & 3) * 8;

  f32x4 acc[16] = {};

  for (int kt = 0; kt < KP / 32; ++kt) {
    const int k0 = kt * 32;
#pragma unroll
    for (int q = 0; q < 4; ++q) {
      int chunk = q * 4 + wave;
      const unsigned short* gsrc;
      if (chunk < 8) {
        int row = m0 + chunk * 16 + lrow;
        gsrc = A + (size_t)row * KP + k0 + lcol;
      } else {
        int row = n0 + (chunk - 8) * 16 + lrow;
        gsrc = Bt + (size_t)row * KP + k0 + lcol;
      }
      gload_lds16(gsrc, &smem[chunk * 512]);
    }
    asm volatile("s_waitcnt vmcnt(0)" ::: "memory");
    __syncthreads();

    bf16x8 af[4], bfr[4];
#pragma unroll
    for (int tm = 0; tm < 4; ++tm)
      af[tm] = ((const bf16x8*)smem)[((wm * 64 + tm * 16 + fr) * 32 + quad * 8) >> 3];
#pragma unroll
    for (int tn = 0; tn < 4; ++tn)
      bfr[tn] = ((const bf16x8*)smem)[(4096 + (wn * 64 + tn * 16 + fr) * 32 + quad * 8) >> 3];
#pragma unroll
    for (int tm = 0; tm < 4; ++tm)
#pragma unroll
      for (int tn = 0; tn < 4; ++tn)
        acc[tm * 4 + tn] = __builtin_amdgcn_mfma_f32_16x16x32_bf16(
            af[tm], bfr[tn], acc[tm * 4 + tn], 0, 0, 0);
    __syncthreads();
  }

#pragma unroll
  for (int tm = 0; tm < 4; ++tm) {
    const int mbase = m0 + wm * 64 + tm * 16 + quad * 4;
    float s1[4] = {0.f, 0.f, 0.f, 0.f}, s2[4] = {0.f, 0.f, 0.f, 0.f};
#pragma unroll
    for (int tn = 0; tn < 4; ++tn) {
      int n = n0 + wn * 64 + tn * 16 + fr;   // batch, coalesced
#pragma unroll
      for (int r = 0; r < 4; ++r) {
        int m = mbase + r;
        float v = acc[tm * 4 + tn][r] + bias[m];
        if (m < 3000) {                      // layer-0 tanh + stats
          v = tanhf(v);
          s1[r] += v; s2[r] += v * v;
        }
        C[(size_t)m * BATCH + n] = v;
      }
    }
    // reduce the 16 fr-lanes (same m, different n) and atomically accumulate
#pragma unroll
    for (int r = 0; r < 4; ++r) {
      int m = mbase + r;
      if (m < 3000) {
        float a = s1[r], q = s2[r];
        a += __shfl_xor(a, 1);  q += __shfl_xor(q, 1);
        a += __shfl_xor(a, 2);  q += __shfl_xor(q, 2);
        a += __shfl_xor(a, 4);  q += __shfl_xor(q, 4);
        a += __shfl_xor(a, 8);  q += __shfl_xor(q, 8);
        if (fr == 0) {
          atomicAdd(&st0[2 * m], a);
          atomicAdd(&st0[2 * m + 1], q);
        }
      }
    }
  }
}

// ---- shared device body: normalize zT + transpose-emit to out[b][outoff+c] ----
__device__ void norm_emit_body(const float* __restrict__ zT, const float* __restrict__ st,
                               const float* __restrict__ gam, const float* __restrict__ bet,
                               float* __restrict__ out, int ncols, int outoff,
                               int xb, int yb) {
  __shared__ float tile[64][65];
  int lane = threadIdx.x & 63, w = threadIdx.x >> 6;
  int c0 = xb * 64, b0 = yb * 64;
#pragma unroll
  for (int i = 0; i < 16; ++i) {
    int cc = w * 16 + i, c = c0 + cc;
    float n = 0.f;
    if (c < ncols) {
      float sc, sh; bn_ss(st, gam, bet, c, sc, sh);
      n = zT[(size_t)c * BATCH + b0 + lane] * sc + sh;
    }
    tile[cc][lane] = n;
  }
  __syncthreads();
  int c = c0 + lane;
  if (c < ncols) {
#pragma unroll
    for (int i = 0; i < 16; ++i) {
      int rr = w * 16 + i;
      out[(size_t)(b0 + rr) * OUTW + outoff + c] = tile[lane][rr];
    }
  }
}

// ========== dispatch 3: norm_emit(n0) + aux0 -> auxT + layer1(+stats) ==========
// ranges: [0,3008) norm_emit0 | [3008,11008) aux0 | [11008,11840) layer1
__global__ __launch_bounds__(256) void fused_l1(
    const float* __restrict__ C, const float* __restrict__ st0,
    const float* __restrict__ gam0, const float* __restrict__ bet0,
    const float* __restrict__ aw0, const float* __restrict__ ab0,
    const float* __restrict__ av0, const float* __restrict__ ac0,
    const float* __restrict__ W1, const float* __restrict__ b1,
    float* __restrict__ out, float* __restrict__ auxT,
    float* __restrict__ z1T, float* __restrict__ st1) {
  int blk = blockIdx.x;
  if (blk < 3008) {
    norm_emit_body(C, st0, gam0, bet0, out, 3000, 551, blk % 47, blk / 47);
  } else if (blk < 11008) {               // ---- aux0 (coalesced write to auxT)
    int b2 = blk - 3008;
    int lane = threadIdx.x & 63, tg = threadIdx.x >> 6;
    int t = (b2 % 125) * 4 + tg;
    int b = (b2 / 125) * 64 + lane;
    float s = ab0[t];
#pragma unroll
    for (int h = 0; h < HID; ++h) {
      int c = t * HID + h;
      float sc, sh; bn_ss(st0, gam0, bet0, c, sc, sh);
      s += (C[(size_t)c * BATCH + b] * sc + sh) * aw0[c];
    }
    auxT[(size_t)t * BATCH + b] = tanhf(s) * av0[t] + ac0[t];
  } else {                                // ---- layer1 + fused stats
    int b3 = blk - 11008;
    int lane = threadIdx.x & 63, tg = threadIdx.x >> 6;
    int t = (b3 % 13) * 4 + tg;
    if (t >= T1N) return;
    int b = (b3 / 13) * 64 + lane;
    const float* dgm = C + (size_t)3000 * BATCH;
    float x[90];
#pragma unroll
    for (int j = 0; j < 60; ++j) {
      int c = t * 60 + j;
      float sc, sh; bn_ss(st0, gam0, bet0, c, sc, sh);
      x[j] = C[(size_t)c * BATCH + b] * sc + sh;
    }
#pragma unroll
    for (int g = 0; g < GPT; ++g)
      x[60 + g] = dgm[(size_t)(t * GPT + g) * BATCH + b];
#pragma unroll
    for (int h = 0; h < HID; ++h) {
      int c = t * HID + h;
      const float* w = W1 + c * 90;
      float s = b1[c];
#pragma unroll
      for (int i = 0; i < 90; ++i) s += x[i] * w[i];
      float z = tanhf(s);
      z1T[(size_t)c * BATCH + b] = z;
      float s1 = z, s2 = z * z;
#pragma unroll
      for (int off = 32; off > 0; off >>= 1) {
        s1 += __shfl_down(s1, off);
        s2 += __shfl_down(s2, off);
      }
      if (lane == 0) {
        atomicAdd(&st1[2 * c], s1);
        atomicAdd(&st1[2 * c + 1], s2);
      }
    }
  }
}

// ========== dispatch 4: norm_emit(n1) + aux1 -> auxT + root(+stats) ==========
// ranges: [0,320) norm_emit1 | [320,1152) aux1 | [1152,1168) root
__global__ __launch_bounds__(256) void fused_l2(
    const float* __restrict__ C, const float* __restrict__ z1T,
    const float* __restrict__ st1,
    const float* __restrict__ gam1, const float* __restrict__ bet1,
    const float* __restrict__ aw1, const float* __restrict__ ab1,
    const float* __restrict__ av1, const float* __restrict__ ac1,
    const float* __restrict__ W2, const float* __restrict__ b2,
    float* __restrict__ out, float* __restrict__ auxT,
    float* __restrict__ z2T, float* __restrict__ st2) {
  int blk = blockIdx.x;
  if (blk < 320) {
    norm_emit_body(z1T, st1, gam1, bet1, out, 300, 3551, blk % 5, blk / 5);
  } else if (blk < 1152) {                // ---- aux1
    int b2 = blk - 320;
    int lane = threadIdx.x & 63, tg = threadIdx.x >> 6;
    int t = (b2 % 13) * 4 + tg;
    if (t >= T1N) return;
    int b = (b2 / 13) * 64 + lane;
    float s = ab1[t];
#pragma unroll
    for (int h = 0; h < HID; ++h) {
      int c = t * HID + h;
      float sc, sh; bn_ss(st1, gam1, bet1, c, sc, sh);
      s += (z1T[(size_t)c * BATCH + b] * sc + sh) * aw1[c];
    }
    auxT[(size_t)(T0N + t) * BATCH + b] = tanhf(s) * av1[t] + ac1[t];
  } else {                                // ---- root z2 + stats
    int b = (blk - 1152) * 256 + threadIdx.x;
    int lane = threadIdx.x & 63;
    const float* dgr = C + (size_t)4500 * BATCH;
    float s[HID];
#pragma unroll
    for (int h = 0; h < HID; ++h) s[h] = b2[h];
    for (int c = 0; c < 300; ++c) {
      float sc, sh; bn_ss(st1, gam1, bet1, c, sc, sh);
      float n = z1T[(size_t)c * BATCH + b] * sc + sh;
#pragma unroll
      for (int h = 0; h < HID; ++h) s[h] += n * W2[h * 330 + c];
    }
#pragma unroll
    for (int g = 0; g < GPT; ++g) {
      float d = dgr[(size_t)g * BATCH + b];
#pragma unroll
      for (int h = 0; h < HID; ++h) s[h] += d * W2[h * 330 + 300 + g];
    }
#pragma unroll
    for (int h = 0; h < HID; ++h) {
      float z = tanhf(s[h]);
      z2T[(size_t)h * BATCH + b] = z;
      float s1 = z, s2 = z * z;
#pragma unroll
      for (int off = 32; off > 0; off >>= 1) {
        s1 += __shfl_down(s1, off);
        s2 += __shfl_down(s2, off);
      }
      if (lane == 0) {
        atomicAdd(&st2[2 * h], s1);
        atomicAdd(&st2[2 * h + 1], s2);
      }
    }
  }
}

// ========== dispatch 5: auxT transpose-emit (550 cols) + n2/aux2 emit ==========
// ranges: [0,576) transpose | [576,592) root finalize
__global__ __launch_bounds__(256) void fused_fin(
    const float* __restrict__ auxT, const float* __restrict__ z2T,
    const float* __restrict__ st2,
    const float* __restrict__ gam2, const float* __restrict__ bet2,
    const float* __restrict__ aw2, const float* __restrict__ ab2,
    const float* __restrict__ av2, const float* __restrict__ ac2,
    float* __restrict__ out) {
  int blk = blockIdx.x;
  if (blk < 576) {
    __shared__ float tile[64][65];
    int lane = threadIdx.x & 63, w = threadIdx.x >> 6;
    int c0 = (blk % 9) * 64, b0 = (blk / 9) * 64;
#pragma unroll
    for (int i = 0; i < 16; ++i) {
      int cc = w * 16 + i, c = c0 + cc;
      tile[cc][lane] = (c < 550) ? auxT[(size_t)c * BATCH + b0 + lane] : 0.f;
    }
    __syncthreads();
    int c = c0 + lane;
    if (c < 550) {
#pragma unroll
      for (int i = 0; i < 16; ++i) {
        int rr = w * 16 + i;
        out[(size_t)(b0 + rr) * OUTW + c] = tile[lane][rr];
      }
    }
  } else {
    int b = (blk - 576) * 256 + threadIdx.x;
    float s = ab2[0];
#pragma unroll
    for (int h = 0; h < HID; ++h) {
      float sc, sh; bn_ss(st2, gam2, bet2, h, sc, sh);
      float n = z2T[(size_t)h * BATCH + b] * sc + sh;
      out[(size_t)b * OUTW + 3851 + h] = n;
      s += n * aw2[h];
    }
    out[(size_t)b * OUTW + 550] = tanhf(s) * av2[0] + ac2[0];
  }
}

extern "C" void kernel_launch(void* const* d_in, const int* in_sizes, int n_in,
                              void* d_out, int out_size, void* d_ws, size_t ws_size,
                              hipStream_t stream) {
  (void)in_sizes; (void)n_in; (void)out_size; (void)ws_size;
  const float* cell = (const float*)d_in[0];
  const float* Wdg  = (const float*)d_in[1];
  const float* bdg  = (const float*)d_in[2];
  const float* W0   = (const float*)d_in[3];
  const float* b0   = (const float*)d_in[4];
  const float* gam0 = (const float*)d_in[5];
  const float* bet0 = (const float*)d_in[6];
  const float* aw0  = (const float*)d_in[7];
  const float* ab0  = (const float*)d_in[8];
  const float* av0  = (const float*)d_in[9];
  const float* ac0  = (const float*)d_in[10];
  const float* W1   = (const float*)d_in[11];
  const float* b1   = (const float*)d_in[12];
  const float* gam1 = (const float*)d_in[13];
  const float* bet1 = (const float*)d_in[14];
  const float* aw1  = (const float*)d_in[15];
  const float* ab1  = (const float*)d_in[16];
  const float* av1  = (const float*)d_in[17];
  const float* ac1  = (const float*)d_in[18];
  const float* W2   = (const float*)d_in[19];
  const float* b2   = (const float*)d_in[20];
  const float* gam2 = (const float*)d_in[21];
  const float* bet2 = (const float*)d_in[22];
  const float* aw2  = (const float*)d_in[23];
  const float* ab2  = (const float*)d_in[24];
  const float* av2  = (const float*)d_in[25];
  const float* ac2  = (const float*)d_in[26];
  float* out = (float*)d_out;

  char* ws = (char*)d_ws;
  unsigned short* cellb = (unsigned short*)(ws);               // 24,641,536
  unsigned short* abuf  = (unsigned short*)(ws + 24641536);    // 27,721,728
  float*          C     = (float*)(ws + 52363264);             // 75,497,472
  float*          z1T   = (float*)(ws + 127860736);            // 4,915,200
  float*          z2T   = (float*)(ws + 132775936);            // 98,304
  float*          st    = (float*)(ws + 132874240);            // 26,448 (pad)
  float*          bias  = (float*)(ws + 132907008);            // 18,432
  float*          auxT  = (float*)(ws + 132925440);            // 9,027,584
  float* st0 = st, *st1 = st + 2 * 3000, *st2 = st + 2 * 3300;

  prep<<<14423, 256, 0, stream>>>(cell, Wdg, W0, b0, bdg,
                                  (ushort8*)cellb, abuf, bias, st);
  gemm_fused<<<dim3(32, 36), 256, 0, stream>>>(abuf, cellb, bias, C, st0);
  fused_l1<<<11840, 256, 0, stream>>>(C, st0, gam0, bet0, aw0, ab0, av0, ac0,
                                      W1, b1, out, auxT, z1T, st1);
  fused_l2<<<1168, 256, 0, stream>>>(C, z1T, st1, gam1, bet1, aw1, ab1, av1, ac1,
                                     W2, b2, out, auxT, z2T, st2);
  fused_fin<<<592, 256, 0, stream>>>(auxT, z2T, st2, gam2, bet2, aw2, ab2, av2, ac2,
                                     out);
}